// Round 14
// baseline (153.802 us; speedup 1.0000x reference)
//
#include <hip/hip_runtime.h>
#include <math.h>

#define N_STATES 32
#define N_TYPES 128
#define N_GENES 8192
#define N_SAMPLES 8192
#define N_TOT (N_SAMPLES * N_GENES)
#define LOG2PI_F 1.8378770664093453f

typedef float f32x2 __attribute__((ext_vector_type(2)));
typedef float f32x4 __attribute__((ext_vector_type(4)));
typedef unsigned int u32x2 __attribute__((ext_vector_type(2)));
typedef unsigned int u32x4 __attribute__((ext_vector_type(4)));

// round-to-nearest-even bf16 (upper 16 bits)
__device__ __forceinline__ unsigned int bf16r(float f) {
  unsigned int u = __builtin_bit_cast(unsigned int, f);
  return (u + 0x7FFFu + ((u >> 16) & 1u)) >> 16;
}

// logp from x and packed table entry (bf16 mu | bf16 inv)
__device__ __forceinline__ float logp_pk(float x, unsigned int tv) {
  float mu = __builtin_bit_cast(float, tv & 0xFFFF0000u);
  float iv = __builtin_bit_cast(float, tv << 16);
  float z = (x - mu) * iv;
  // logp = -0.5 z^2 - log(sigma) - 0.5 log(2pi);  log(sigma) = -log(inv)
  return fmaf(-0.5f * z, z, __logf(iv) - 0.5f * LOG2PI_F);
}

// ---------------- Kernel 1: packed per-(state,gene) table ----------------
// T[st,g] = bf16(mu)<<16 | bf16(1/sigma).  4 states/block, 512-gene chunks,
// 2 genes/thread: Z re-read 8x, 128 blocks. 1 MB -> L2-resident.
__global__ __launch_bounds__(256) void precompute_kernel(
    const float* __restrict__ cp, const float* __restrict__ Zmu,
    const float* __restrict__ Zs, unsigned int* __restrict__ T) {
  __shared__ float s_cp[4][N_TYPES], s_cp2[4][N_TYPES];
  const int st0 = blockIdx.y * 4;
  const int g0 = blockIdx.x * 512 + threadIdx.x * 2;

  for (int idx = threadIdx.x; idx < 4 * N_TYPES; idx += 256) {
    int s = idx >> 7, t = idx & (N_TYPES - 1);
    float c = cp[(st0 + s) * N_TYPES + t];
    s_cp[s][t] = c;
    s_cp2[s][t] = c * c;
  }
  __syncthreads();

  float mu[4][2] = {}, s2a[4][2] = {}, s13[4][2] = {};
#pragma unroll 1
  for (int t = 0; t < N_TYPES; t += 2) {
    f32x2 zm0 = *(const f32x2*)(Zmu + (size_t)t * N_GENES + g0);
    f32x2 zs0 = *(const f32x2*)(Zs  + (size_t)t * N_GENES + g0);
    f32x2 zm1 = *(const f32x2*)(Zmu + (size_t)(t + 1) * N_GENES + g0);
    f32x2 zs1 = *(const f32x2*)(Zs  + (size_t)(t + 1) * N_GENES + g0);
    f32x2 q0, q1;
#pragma unroll
    for (int j = 0; j < 2; ++j) {
      q0[j] = zs0[j] * (1.f - zs0[j]);
      q1[j] = zs1[j] * (1.f - zs1[j]);
    }
#pragma unroll
    for (int s = 0; s < 4; ++s) {
      float c0 = s_cp[s][t], c20 = s_cp2[s][t];
      float c1 = s_cp[s][t + 1], c21 = s_cp2[s][t + 1];
#pragma unroll
      for (int j = 0; j < 2; ++j) {
        mu[s][j]  = fmaf(c0, zm0[j], mu[s][j]);
        s2a[s][j] = fmaf(c0, zs0[j], s2a[s][j]);
        s13[s][j] = fmaf(c20, q0[j], s13[s][j]);
        mu[s][j]  = fmaf(c1, zm1[j], mu[s][j]);
        s2a[s][j] = fmaf(c1, zs1[j], s2a[s][j]);
        s13[s][j] = fmaf(c21, q1[j], s13[s][j]);
      }
    }
  }

#pragma unroll
  for (int s = 0; s < 4; ++s) {
    u32x2 pk;
#pragma unroll
    for (int j = 0; j < 2; ++j) {
      float sigma = s13[s][j] + s2a[s][j] * s2a[s][j];
      pk[j] = (bf16r(mu[s][j]) << 16) | bf16r(1.0f / sigma);
    }
    *(u32x2*)(T + (size_t)(st0 + s) * N_GENES + g0) = pk;
  }
}

// ---------------- Kernel 2: main. 1 row/block, 512 threads, depth-4 batch ----
// Loads shifted -1 element (clamped at 0) -> stores are ALIGNED NT f32x4:
// out[row*NG + it*2048 + 4*tid .. +3] holds logp[same - 1 .. +2].
// NO __syncthreads / NO LDS in the epilogue: each wave writes its own partial
// (partial[block*8 + wave]) so the block retires without draining NT stores
// (__syncthreads would emit s_waitcnt vmcnt(0) -> synchronous HBM drain).
__global__ __launch_bounds__(512) void main_kernel(
    const float* __restrict__ X, const int* __restrict__ day,
    const unsigned int* __restrict__ T, float* __restrict__ out,
    float* __restrict__ partial) {
  const int row = blockIdx.x;
  const int tid = threadIdx.x;
  const int st = day[row] - 1;                        // wave-uniform
  const float* Xr = X + (size_t)row * N_GENES;
  const unsigned int* Tr = T + (size_t)st * N_GENES;
  const int base = 4 * tid - 1;

  f32x4 xb[4];
  u32x4 tb[4];
#pragma unroll
  for (int it = 0; it < 4; ++it) {
    int o = it * 2048 + base;
    if (o < 0) o = 0;                                 // only (tid==0, it==0)
    __builtin_memcpy(&xb[it], Xr + o, 16);
  }
#pragma unroll
  for (int it = 0; it < 4; ++it) {
    int o = it * 2048 + base;
    if (o < 0) o = 0;
    __builtin_memcpy(&tb[it], Tr + o, 16);
  }
  __builtin_amdgcn_sched_barrier(0x6);                // pin load batch

  float acc = 0.f;
  float* outr = out + (size_t)row * N_GENES + 4 * tid;
#pragma unroll
  for (int it = 0; it < 4; ++it) {
    f32x4 p;
#pragma unroll
    for (int j = 0; j < 4; ++j) p[j] = logp_pk(xb[it][j], tb[it][j]);
    if (it == 0 && tid == 0) {
      // clamped loads gave elements 0..3 of this row: shift lanes by 1
      p[3] = p[2]; p[2] = p[1]; p[1] = p[0];
      float p0 = 0.f;
      if (row > 0) {                                  // logp[row*NG - 1]
        int stP = day[row - 1] - 1;
        p0 = logp_pk(X[(size_t)row * N_GENES - 1],
                     T[(size_t)stP * N_GENES + N_GENES - 1]);
      }
      p[0] = p0;                                      // row 0: junk, reduce fixes
    }
    __builtin_nontemporal_store(p, (f32x4*)(outr + it * 2048));
    acc += (p[0] + p[1]) + (p[2] + p[3]);
  }

  // last logp element (N_TOT-1) is outside every shifted window
  if (row == N_SAMPLES - 1 && tid == 511) {
    float p = logp_pk(X[(size_t)N_TOT - 1],
                      T[(size_t)st * N_GENES + N_GENES - 1]);
    out[N_TOT] = p;
    acc += p;
  }

  // wave-level reduce only; one partial per wave, no barrier
#pragma unroll
  for (int off = 32; off; off >>= 1) acc += __shfl_down(acc, off, 64);
  if ((tid & 63) == 0) partial[blockIdx.x * 8 + (tid >> 6)] = acc;
}

// ---------------- Kernel 3: final reduction (deterministic, double) ----------------
__global__ __launch_bounds__(1024) void reduce_kernel(
    const float* __restrict__ partial, int n, float* __restrict__ out0) {
  double acc = 0.0;
  for (int i = threadIdx.x; i < n; i += 1024) acc += (double)partial[i];
#pragma unroll
  for (int off = 32; off; off >>= 1) acc += __shfl_down(acc, off, 64);
  __shared__ double s_w[16];
  int lane = threadIdx.x & 63, w = threadIdx.x >> 6;
  if (lane == 0) s_w[w] = acc;
  __syncthreads();
  if (threadIdx.x == 0) {
    double s = 0.0;
#pragma unroll
    for (int i = 0; i < 16; ++i) s += s_w[i];
    out0[0] = (float)s;
  }
}

extern "C" void kernel_launch(void* const* d_in, const int* in_sizes, int n_in,
                              void* d_out, int out_size, void* d_ws, size_t ws_size,
                              hipStream_t stream) {
  const float* cp  = (const float*)d_in[0];   // (32,128)
  const float* Zmu = (const float*)d_in[1];   // (128,8192)
  const float* Zs  = (const float*)d_in[2];   // (128,8192)
  const float* X   = (const float*)d_in[3];   // (8192,8192)
  const int*   day = (const int*)d_in[4];     // (8192,)
  float* out = (float*)d_out;                 // [0]=sum, [1..]=logp flat
  float* ws  = (float*)d_ws;

  const int TBL = N_STATES * N_GENES;         // 262144
  unsigned int* T = (unsigned int*)ws;        // 1 MB packed table
  float* partial  = ws + TBL;                 // 8192*8 = 65536 floats

  dim3 g1(N_GENES / 512, N_STATES / 4);       // 16 x 8 = 128 blocks
  precompute_kernel<<<g1, 256, 0, stream>>>(cp, Zmu, Zs, T);

  main_kernel<<<N_SAMPLES, 512, 0, stream>>>(X, day, T, out, partial);
  reduce_kernel<<<1, 1024, 0, stream>>>(partial, N_SAMPLES * 8, out);
}

// Round 15
// 125.109 us; speedup vs baseline: 1.2294x; 1.2294x over previous
//
#include <hip/hip_runtime.h>
#include <math.h>

#define N_STATES 32
#define N_TYPES 128
#define N_GENES 8192
#define N_SAMPLES 8192
#define N_TOT (N_SAMPLES * N_GENES)
#define LOG2PI_F 1.8378770664093453f

typedef float f32x2 __attribute__((ext_vector_type(2)));
typedef float f32x4 __attribute__((ext_vector_type(4)));
typedef unsigned int u32x2 __attribute__((ext_vector_type(2)));
typedef unsigned int u32x4 __attribute__((ext_vector_type(4)));

// round-to-nearest-even bf16 (upper 16 bits)
__device__ __forceinline__ unsigned int bf16r(float f) {
  unsigned int u = __builtin_bit_cast(unsigned int, f);
  return (u + 0x7FFFu + ((u >> 16) & 1u)) >> 16;
}

// logp from x and packed table entry (bf16 mu | bf16 inv)
__device__ __forceinline__ float logp_pk(float x, unsigned int tv) {
  float mu = __builtin_bit_cast(float, tv & 0xFFFF0000u);
  float iv = __builtin_bit_cast(float, tv << 16);
  float z = (x - mu) * iv;
  // logp = -0.5 z^2 - log(sigma) - 0.5 log(2pi);  log(sigma) = -log(inv)
  return fmaf(-0.5f * z, z, __logf(iv) - 0.5f * LOG2PI_F);
}

// ---------------- Kernel 1: packed per-(state,gene) table ----------------
// T[st,g] = bf16(mu)<<16 | bf16(1/sigma).  4 states/block, 512-gene chunks,
// 2 genes/thread. 1 MB -> L2-resident.
__global__ __launch_bounds__(256) void precompute_kernel(
    const float* __restrict__ cp, const float* __restrict__ Zmu,
    const float* __restrict__ Zs, unsigned int* __restrict__ T) {
  __shared__ float s_cp[4][N_TYPES], s_cp2[4][N_TYPES];
  const int st0 = blockIdx.y * 4;
  const int g0 = blockIdx.x * 512 + threadIdx.x * 2;

  for (int idx = threadIdx.x; idx < 4 * N_TYPES; idx += 256) {
    int s = idx >> 7, t = idx & (N_TYPES - 1);
    float c = cp[(st0 + s) * N_TYPES + t];
    s_cp[s][t] = c;
    s_cp2[s][t] = c * c;
  }
  __syncthreads();

  float mu[4][2] = {}, s2a[4][2] = {}, s13[4][2] = {};
#pragma unroll 1
  for (int t = 0; t < N_TYPES; t += 2) {
    f32x2 zm0 = *(const f32x2*)(Zmu + (size_t)t * N_GENES + g0);
    f32x2 zs0 = *(const f32x2*)(Zs  + (size_t)t * N_GENES + g0);
    f32x2 zm1 = *(const f32x2*)(Zmu + (size_t)(t + 1) * N_GENES + g0);
    f32x2 zs1 = *(const f32x2*)(Zs  + (size_t)(t + 1) * N_GENES + g0);
    f32x2 q0, q1;
#pragma unroll
    for (int j = 0; j < 2; ++j) {
      q0[j] = zs0[j] * (1.f - zs0[j]);
      q1[j] = zs1[j] * (1.f - zs1[j]);
    }
#pragma unroll
    for (int s = 0; s < 4; ++s) {
      float c0 = s_cp[s][t], c20 = s_cp2[s][t];
      float c1 = s_cp[s][t + 1], c21 = s_cp2[s][t + 1];
#pragma unroll
      for (int j = 0; j < 2; ++j) {
        mu[s][j]  = fmaf(c0, zm0[j], mu[s][j]);
        s2a[s][j] = fmaf(c0, zs0[j], s2a[s][j]);
        s13[s][j] = fmaf(c20, q0[j], s13[s][j]);
        mu[s][j]  = fmaf(c1, zm1[j], mu[s][j]);
        s2a[s][j] = fmaf(c1, zs1[j], s2a[s][j]);
        s13[s][j] = fmaf(c21, q1[j], s13[s][j]);
      }
    }
  }

#pragma unroll
  for (int s = 0; s < 4; ++s) {
    u32x2 pk;
#pragma unroll
    for (int j = 0; j < 2; ++j) {
      float sigma = s13[s][j] + s2a[s][j] * s2a[s][j];
      pk[j] = (bf16r(mu[s][j]) << 16) | bf16r(1.0f / sigma);
    }
    *(u32x2*)(T + (size_t)(st0 + s) * N_GENES + g0) = pk;
  }
}

// ---------------- Kernel 2: main. 1 row/block, 512 threads, depth-4 batch ----
// ALL loads aligned (own 4 elems); +1 output shift assembled in-register:
// store value = (pred p3, own p0, p1, p2), pred via shfl_up / LDS edge /
// tid0 prev-row recompute. Stores: aligned NT f32x4. TA transactions per
// chunk drop 5 -> 3 (unaligned dwordx4 splits across 2 cachelines).
__global__ __launch_bounds__(512) void main_kernel(
    const float* __restrict__ X, const int* __restrict__ day,
    const unsigned int* __restrict__ T, float* __restrict__ out,
    float* __restrict__ partial) {
  const int row = blockIdx.x;
  const int tid = threadIdx.x;
  const int lane = tid & 63, wv = tid >> 6;
  const int st = day[row] - 1;                        // wave-uniform
  const float* Xr = X + (size_t)row * N_GENES;
  const unsigned int* Tr = T + (size_t)st * N_GENES;

  // tid0 prev-row inputs issued early (overlap with batch)
  float pmx = 0.f; unsigned int pmt = 0;
  if (tid == 0 && row > 0) {
    int stP = day[row - 1] - 1;
    pmx = X[(size_t)row * N_GENES - 1];
    pmt = T[(size_t)stP * N_GENES + N_GENES - 1];
  }

  f32x4 xb[4];
  u32x4 tb[4];
#pragma unroll
  for (int it = 0; it < 4; ++it) {
    int o = it * 2048 + 4 * tid;                      // ALIGNED
    __builtin_memcpy(&xb[it], Xr + o, 16);
  }
#pragma unroll
  for (int it = 0; it < 4; ++it) {
    int o = it * 2048 + 4 * tid;
    __builtin_memcpy(&tb[it], Tr + o, 16);
  }
  __builtin_amdgcn_sched_barrier(0x6);                // pin load batch

  float p[4][4];
  float acc = 0.f;
#pragma unroll
  for (int it = 0; it < 4; ++it) {
#pragma unroll
    for (int j = 0; j < 4; ++j) {
      p[it][j] = logp_pk(xb[it][j], tb[it][j]);
      acc += p[it][j];
    }
  }

  // predecessor p3 per chunk: lanes 1-63 via shfl; wave boundary via LDS
  float sh0[4];
#pragma unroll
  for (int it = 0; it < 4; ++it) sh0[it] = __shfl_up(p[it][3], 1, 64);

  __shared__ float s_edge[8][4];
  if (lane == 63) {
#pragma unroll
    for (int it = 0; it < 4; ++it) s_edge[wv][it] = p[it][3];
  }
  __syncthreads();                                    // only LDS writes pending
  if (lane == 0) {
    if (wv > 0) {
#pragma unroll
      for (int it = 0; it < 4; ++it) sh0[it] = s_edge[wv - 1][it];
    } else {                                          // tid == 0
      sh0[0] = (row > 0) ? logp_pk(pmx, pmt) : 0.f;   // row0: junk, reduce fixes
#pragma unroll
      for (int it = 1; it < 4; ++it) sh0[it] = s_edge[7][it - 1];
    }
  }

  float* outr = out + (size_t)row * N_GENES + 4 * tid;
#pragma unroll
  for (int it = 0; it < 4; ++it) {
    f32x4 v;
    v[0] = sh0[it]; v[1] = p[it][0]; v[2] = p[it][1]; v[3] = p[it][2];
    __builtin_nontemporal_store(v, (f32x4*)(outr + it * 2048));
  }

  // last logp element (N_TOT-1): outside every shifted window (store only;
  // its value is already in acc as an original)
  if (row == N_SAMPLES - 1 && tid == 511) out[N_TOT] = p[3][3];

#pragma unroll
  for (int off = 32; off; off >>= 1) acc += __shfl_down(acc, off, 64);
  __shared__ float s_w[8];
  if (lane == 0) s_w[wv] = acc;
  __syncthreads();
  if (tid == 0) {
    float s = 0.f;
#pragma unroll
    for (int i = 0; i < 8; ++i) s += s_w[i];
    partial[blockIdx.x] = s;
  }
}

// ---------------- Kernel 3: final reduction (deterministic, double) ----------------
__global__ __launch_bounds__(1024) void reduce_kernel(
    const float* __restrict__ partial, int n, float* __restrict__ out0) {
  double acc = 0.0;
  for (int i = threadIdx.x; i < n; i += 1024) acc += (double)partial[i];
#pragma unroll
  for (int off = 32; off; off >>= 1) acc += __shfl_down(acc, off, 64);
  __shared__ double s_w[16];
  int lane = threadIdx.x & 63, w = threadIdx.x >> 6;
  if (lane == 0) s_w[w] = acc;
  __syncthreads();
  if (threadIdx.x == 0) {
    double s = 0.0;
#pragma unroll
    for (int i = 0; i < 16; ++i) s += s_w[i];
    out0[0] = (float)s;
  }
}

extern "C" void kernel_launch(void* const* d_in, const int* in_sizes, int n_in,
                              void* d_out, int out_size, void* d_ws, size_t ws_size,
                              hipStream_t stream) {
  const float* cp  = (const float*)d_in[0];   // (32,128)
  const float* Zmu = (const float*)d_in[1];   // (128,8192)
  const float* Zs  = (const float*)d_in[2];   // (128,8192)
  const float* X   = (const float*)d_in[3];   // (8192,8192)
  const int*   day = (const int*)d_in[4];     // (8192,)
  float* out = (float*)d_out;                 // [0]=sum, [1..]=logp flat
  float* ws  = (float*)d_ws;

  const int TBL = N_STATES * N_GENES;         // 262144
  unsigned int* T = (unsigned int*)ws;        // 1 MB packed table
  float* partial  = ws + TBL;                 // 8192 floats

  dim3 g1(N_GENES / 512, N_STATES / 4);       // 16 x 8 = 128 blocks
  precompute_kernel<<<g1, 256, 0, stream>>>(cp, Zmu, Zs, T);

  main_kernel<<<N_SAMPLES, 512, 0, stream>>>(X, day, T, out, partial);
  reduce_kernel<<<1, 1024, 0, stream>>>(partial, N_SAMPLES, out);
}